// Round 3
// baseline (513.650 us; speedup 1.0000x reference)
//
#include <hip/hip_runtime.h>
#include <hip/hip_cooperative_groups.h>
#include <math.h>

namespace cg = cooperative_groups;

// GCN link predictor, sparse-cone evaluation (round 3).
// Round-2 profile: 8 dispatches x ~10us overhead dominated; device work is
// ~10us. Fix: single cooperative kernel, grid.sync() between phases.
//
// Phases (all inside one launch):
//  P0  zero ctrl/deg/bitmaps (no hipMemsetAsync needed)
//  P1  scan dst: collect e1 = edges with dst in {p0,p1}
//  P2  build F1 = {p0,p1} U src(e1); bmF1 + need bits + pos1
//  P3  zero agg1e[0..nf1); scan dst: collect e2 (dst in F1), need-bit src(e2)
//  P4  scan dst: deg[d]++ only if need-bit[d]   (~10k atomics)
//  P5  agg1e[pos1[u]][c] += dinv[w]dinv[u] x[w][c]  over e2
//  P6  h1[i] = relu((agg1e[i] + dinv[u]^2 x[u]) @ W1 + b1)  (1 wave/row)
//  P7  block 0: agg2 / h2 / fc / sigmoid

#define CH 64
#define E1CAP 4096
#define F1CAP (E1CAP + 2)
#define E2CAP 131072
#define GRID 512
#define TPB 256

struct Params {
    const float* x; const int* src; const int* dst; int E; int N;
    const int* np_;
    const float* W1; const float* b1; const float* W2; const float* b2;
    const float* fcW; const float* fcb;
    float* out;
    int* ctrl; int* deg; unsigned* bmF1; unsigned* bmNd;
    float* agg1e; int* pos1; int* e1s; int* e1d; int* F1;
    int* e2s; int* e2d; float* h1;
};

__device__ __forceinline__ float dinv_of(int degv) { return rsqrtf((float)(degv + 1)); }

__global__ __launch_bounds__(TPB, 2) void k_fused(Params p) {
    cg::grid_group grid = cg::this_grid();
    const int tid = blockIdx.x * blockDim.x + threadIdx.x;
    const int nthreads = gridDim.x * blockDim.x;

    // ---- P0: zero control/deg/bitmaps ----
    for (int i = tid; i < 16; i += nthreads) p.ctrl[i] = 0;
    for (int i = tid; i < p.N; i += nthreads) p.deg[i] = 0;
    const int bmN = (p.N + 31) >> 5;
    for (int i = tid; i < bmN; i += nthreads) { p.bmF1[i] = 0u; p.bmNd[i] = 0u; }
    grid.sync();

    const int p0 = p.np_[0], p1 = p.np_[1];
    const int nvec = p.E >> 2;
    const int4* dst4 = (const int4*)p.dst;

    // ---- P1: e1 collect ----
    for (int i = tid; i < nvec; i += nthreads) {
        int4 d4 = dst4[i];
        int ds[4] = {d4.x, d4.y, d4.z, d4.w};
#pragma unroll
        for (int k = 0; k < 4; k++) {
            int d = ds[k];
            if (d == p0 || d == p1) {
                int e = i * 4 + k;
                int s = p.src[e];
                int idx = atomicAdd(&p.ctrl[0], 1);
                if (idx < E1CAP) { p.e1s[idx] = s; p.e1d[idx] = d; }
            }
        }
    }
    for (int e = (nvec << 2) + tid; e < p.E; e += nthreads) {
        int d = p.dst[e];
        if (d == p0 || d == p1) {
            int s = p.src[e];
            int idx = atomicAdd(&p.ctrl[0], 1);
            if (idx < E1CAP) { p.e1s[idx] = s; p.e1d[idx] = d; }
        }
    }
    grid.sync();

    // ---- P2: build F1 (dedup via bmF1) ----
    {
        int cnt1 = min(p.ctrl[0], E1CAP);
        for (int g = tid; g < cnt1 + 2; g += nthreads) {
            int u = (g < cnt1) ? p.e1s[g] : p.np_[g - cnt1];
            unsigned bit = 1u << (u & 31);
            unsigned old = atomicOr(&p.bmF1[u >> 5], bit);
            if (!(old & bit)) {
                atomicOr(&p.bmNd[u >> 5], bit);
                int i = atomicAdd(&p.ctrl[2], 1);
                p.F1[i] = u;
                p.pos1[u] = i;
            }
        }
    }
    grid.sync();

    // ---- P3: zero agg1e rows; e2 collect + need marks ----
    {
        int nf1 = min(p.ctrl[2], F1CAP);
        for (int i = tid; i < nf1 * CH; i += nthreads) p.agg1e[i] = 0.f;
        for (int i = tid; i < nvec; i += nthreads) {
            int4 d4 = dst4[i];
            int ds[4] = {d4.x, d4.y, d4.z, d4.w};
#pragma unroll
            for (int k = 0; k < 4; k++) {
                int d = ds[k];
                if ((p.bmF1[d >> 5] >> (d & 31)) & 1u) {
                    int e = i * 4 + k;
                    int s = p.src[e];
                    atomicOr(&p.bmNd[s >> 5], 1u << (s & 31));
                    int idx = atomicAdd(&p.ctrl[1], 1);
                    if (idx < E2CAP) { p.e2s[idx] = s; p.e2d[idx] = d; }
                }
            }
        }
        for (int e = (nvec << 2) + tid; e < p.E; e += nthreads) {
            int d = p.dst[e];
            if ((p.bmF1[d >> 5] >> (d & 31)) & 1u) {
                int s = p.src[e];
                atomicOr(&p.bmNd[s >> 5], 1u << (s & 31));
                int idx = atomicAdd(&p.ctrl[1], 1);
                if (idx < E2CAP) { p.e2s[idx] = s; p.e2d[idx] = d; }
            }
        }
    }
    grid.sync();

    // ---- P4: conditional degree count ----
    for (int i = tid; i < nvec; i += nthreads) {
        int4 d4 = dst4[i];
        int ds[4] = {d4.x, d4.y, d4.z, d4.w};
#pragma unroll
        for (int k = 0; k < 4; k++) {
            int d = ds[k];
            if ((p.bmNd[d >> 5] >> (d & 31)) & 1u) atomicAdd(&p.deg[d], 1);
        }
    }
    for (int e = (nvec << 2) + tid; e < p.E; e += nthreads) {
        int d = p.dst[e];
        if ((p.bmNd[d >> 5] >> (d & 31)) & 1u) atomicAdd(&p.deg[d], 1);
    }
    grid.sync();

    // ---- P5: layer-1 edge scatter (wave shares edge e, lane = channel) ----
    {
        int cnt2 = min(p.ctrl[1], E2CAP);
        long total = (long)cnt2 * CH;
        for (long idx = tid; idx < total; idx += nthreads) {
            int e = (int)(idx >> 6);
            int c = (int)(idx & 63);
            int w = p.e2s[e], u = p.e2d[e];
            float nrm = dinv_of(p.deg[w]) * dinv_of(p.deg[u]);
            atomicAdd(&p.agg1e[p.pos1[u] * CH + c], nrm * p.x[(size_t)w * CH + c]);
        }
    }
    grid.sync();

    // ---- P6: h1 = relu(agg1 @ W1 + b1), one wave per row ----
    {
        int nf1 = min(p.ctrl[2], F1CAP);
        int wave = tid >> 6, lane = tid & 63;
        int nwaves = nthreads >> 6;
        for (int i = wave; i < nf1; i += nwaves) {
            int u = p.F1[i];
            float di = dinv_of(p.deg[u]);
            float aval = p.agg1e[i * CH + lane] + di * di * p.x[(size_t)u * CH + lane];
            float sum = p.b1[lane];
#pragma unroll 8
            for (int k = 0; k < CH; k++)
                sum += __shfl(aval, k) * p.W1[k * CH + lane];
            p.h1[i * CH + lane] = fmaxf(sum, 0.f);
        }
    }
    grid.sync();

    // ---- P7: tail on block 0 ----
    if (blockIdx.x == 0) {
        __shared__ float a[2][CH];
        __shared__ float partial[2];
        int t = threadIdx.x >> 6, j = threadIdx.x & 63;
        if (threadIdx.x < 128) {
            int pp = p.np_[t];
            float dp = dinv_of(p.deg[pp]);
            float acc = dp * dp * p.h1[p.pos1[pp] * CH + j];
            int cnt1 = min(p.ctrl[0], E1CAP);
            for (int e = 0; e < cnt1; e++) {
                int d = p.e1d[e];
                if (d == pp) {
                    int s = p.e1s[e];
                    acc += dinv_of(p.deg[s]) * dp * p.h1[p.pos1[s] * CH + j];
                }
            }
            a[t][j] = acc;
        }
        __syncthreads();
        if (threadIdx.x < 128) {
            float sum = p.b2[j];
#pragma unroll
            for (int k = 0; k < CH; k++) sum += a[t][k] * p.W2[k * CH + j];
            float v = fmaxf(sum, 0.f);
            float pr = v * p.fcW[t * CH + j];
            for (int off = 32; off > 0; off >>= 1) pr += __shfl_down(pr, off);
            if (j == 0) partial[t] = pr;
        }
        __syncthreads();
        if (threadIdx.x == 0) {
            float z = partial[0] + partial[1] + p.fcb[0];
            p.out[0] = 1.f / (1.f + expf(-z));
        }
    }
}

extern "C" void kernel_launch(void* const* d_in, const int* in_sizes, int n_in,
                              void* d_out, int out_size, void* d_ws, size_t ws_size,
                              hipStream_t stream) {
    Params p;
    p.x   = (const float*)d_in[0];
    const int* ei = (const int*)d_in[1];
    p.np_ = (const int*)d_in[2];
    p.W1  = (const float*)d_in[3];
    p.b1  = (const float*)d_in[4];
    p.W2  = (const float*)d_in[5];
    p.b2  = (const float*)d_in[6];
    p.fcW = (const float*)d_in[7];
    p.fcb = (const float*)d_in[8];
    p.out = (float*)d_out;

    p.N = in_sizes[0] / CH;
    p.E = in_sizes[1] / 2;
    p.src = ei;
    p.dst = ei + p.E;

    char* w = (char*)d_ws;
    size_t off = 0;
    auto alloc = [&](size_t bytes) {
        size_t o = off;
        off = (off + bytes + 255) & ~((size_t)255);
        return o;
    };
    size_t o_ctrl  = alloc(64);
    size_t o_deg   = alloc((size_t)p.N * 4);
    int bmN = (p.N + 31) / 32;
    size_t o_bmF1  = alloc((size_t)bmN * 4);
    size_t o_bmNd  = alloc((size_t)bmN * 4);
    size_t o_agg1e = alloc((size_t)F1CAP * CH * 4);
    size_t o_pos   = alloc((size_t)p.N * 4);
    size_t o_e1s   = alloc((size_t)E1CAP * 4);
    size_t o_e1d   = alloc((size_t)E1CAP * 4);
    size_t o_F1    = alloc((size_t)F1CAP * 4);
    size_t o_e2s   = alloc((size_t)E2CAP * 4);
    size_t o_e2d   = alloc((size_t)E2CAP * 4);
    size_t o_h1    = alloc((size_t)F1CAP * CH * 4);
    (void)ws_size;

    p.ctrl  = (int*)(w + o_ctrl);
    p.deg   = (int*)(w + o_deg);
    p.bmF1  = (unsigned*)(w + o_bmF1);
    p.bmNd  = (unsigned*)(w + o_bmNd);
    p.agg1e = (float*)(w + o_agg1e);
    p.pos1  = (int*)(w + o_pos);
    p.e1s   = (int*)(w + o_e1s);
    p.e1d   = (int*)(w + o_e1d);
    p.F1    = (int*)(w + o_F1);
    p.e2s   = (int*)(w + o_e2s);
    p.e2d   = (int*)(w + o_e2d);
    p.h1    = (float*)(w + o_h1);

    void* args[] = { &p };
    hipLaunchCooperativeKernel((void*)k_fused, dim3(GRID), dim3(TPB), args, 0, stream);
}

// Round 4
// 343.816 us; speedup vs baseline: 1.4940x; 1.4940x over previous
//
#include <hip/hip_runtime.h>
#include <math.h>

// GCN link predictor, sparse-cone evaluation (round 4).
// Round-3 lesson: cg::grid.sync() costs ~58us/sync on 8-XCD MI355X (413us
// kernel, 0.3% VALUBusy). Replace with hand-rolled device-scope barrier
// (threadfence + atomic counter + relaxed spin w/ s_sleep). Tiny phases run
// in the LAST-arriving block of the preceding barrier:
//   bar0: after zero(deg/bitmaps)
//   bar1: after e1 scan; last block builds F1 + marks bmNd + zeroes agg1e rows
//   bar2: after e2 scan (+bmNd source marks)
//   bar3: after conditional deg scan
//   bar4: after agg1e scatter; last block: W1->LDS, h1 GEMV, layer2+fc tail.
//         Non-last blocks arrive and exit (no spin).

#define CH 64
#define E1CAP 4096
#define F1CAP (E1CAP + 2)
#define E2CAP 131072
#define GRID 512
#define TPB 256

struct Params {
    const float* x; const int* src; const int* dst; int E; int N;
    const int* np_;
    const float* W1; const float* b1; const float* W2; const float* b2;
    const float* fcW; const float* fcb;
    float* out;
    int* ctrl;           // [0]=cnt_e1 [1]=cnt_e2 [2]=nf1, [8..12]=bar cnt, [16..20]=bar flag
    int* deg; unsigned* bmF1; unsigned* bmNd;
    float* agg1e; int* pos1; int* e1s; int* e1d; int* F1;
    int* e2s; int* e2d; float* h1;
};

__device__ __forceinline__ float dinv_of(int degv) { return rsqrtf((float)(degv + 1)); }

// returns true in ALL threads of the last-arriving block
__device__ __forceinline__ bool bar_arrive(int* cnt, int nblk) {
    __shared__ int is_last;
    __syncthreads();
    if (threadIdx.x == 0) {
        __threadfence();   // release my writes
        int t = __hip_atomic_fetch_add(cnt, 1, __ATOMIC_ACQ_REL, __HIP_MEMORY_SCOPE_AGENT);
        if (t == nblk - 1) __threadfence();  // acquire everyone's writes
        is_last = (t == nblk - 1) ? 1 : 0;
    }
    __syncthreads();
    return is_last != 0;
}

__device__ __forceinline__ void bar_release(int* flag) {
    __syncthreads();
    if (threadIdx.x == 0) {
        __threadfence();
        __hip_atomic_store(flag, 1, __ATOMIC_RELEASE, __HIP_MEMORY_SCOPE_AGENT);
    }
}

__device__ __forceinline__ void bar_wait(int* flag) {
    if (threadIdx.x == 0) {
        while (__hip_atomic_load(flag, __ATOMIC_RELAXED, __HIP_MEMORY_SCOPE_AGENT) == 0)
            __builtin_amdgcn_s_sleep(1);
        __threadfence();   // acquire
    }
    __syncthreads();
}

__global__ __launch_bounds__(TPB, 2) void k_fused(Params p) {
    const int tid = blockIdx.x * blockDim.x + threadIdx.x;
    const int nthreads = gridDim.x * blockDim.x;
    int* ctrl = p.ctrl;

    const int p0 = p.np_[0], p1 = p.np_[1];
    const int nvec = p.E >> 2;
    const int4* dst4 = (const int4*)p.dst;

    // ---- P0: zero deg + bitmaps (ctrl/barrier state zeroed by host memset) ----
    {
        int4 z4 = make_int4(0, 0, 0, 0);
        int nd4 = p.N >> 2;
        int4* deg4 = (int4*)p.deg;
        for (int i = tid; i < nd4; i += nthreads) deg4[i] = z4;
        for (int i = (nd4 << 2) + tid; i < p.N; i += nthreads) p.deg[i] = 0;
        const int bmN = (p.N + 31) >> 5;
        for (int i = tid; i < bmN; i += nthreads) { p.bmF1[i] = 0u; p.bmNd[i] = 0u; }
    }
    if (bar_arrive(&ctrl[8], GRID)) bar_release(&ctrl[16]); else bar_wait(&ctrl[16]);

    // ---- P1: e1 scan (dst in {p0,p1}) ----
    for (int i = tid; i < nvec; i += nthreads) {
        int4 d4 = dst4[i];
        int ds[4] = {d4.x, d4.y, d4.z, d4.w};
#pragma unroll
        for (int k = 0; k < 4; k++) {
            int d = ds[k];
            if (d == p0 || d == p1) {
                int s = p.src[i * 4 + k];
                int idx = atomicAdd(&ctrl[0], 1);
                if (idx < E1CAP) { p.e1s[idx] = s; p.e1d[idx] = d; }
            }
        }
    }
    for (int e = (nvec << 2) + tid; e < p.E; e += nthreads) {
        int d = p.dst[e];
        if (d == p0 || d == p1) {
            int s = p.src[e];
            int idx = atomicAdd(&ctrl[0], 1);
            if (idx < E1CAP) { p.e1s[idx] = s; p.e1d[idx] = d; }
        }
    }
    // ---- bar1: last block builds F1 + zeroes agg1e rows ----
    if (bar_arrive(&ctrl[9], GRID)) {
        int cnt1 = min(ctrl[0], E1CAP);
        for (int g = threadIdx.x; g < cnt1 + 2; g += TPB) {
            int u = (g < cnt1) ? p.e1s[g] : ((g - cnt1) ? p1 : p0);
            unsigned bit = 1u << (u & 31);
            unsigned old = atomicOr(&p.bmF1[u >> 5], bit);
            if (!(old & bit)) {
                atomicOr(&p.bmNd[u >> 5], bit);
                int i = atomicAdd(&ctrl[2], 1);
                p.F1[i] = u;
                p.pos1[u] = i;
            }
        }
        __syncthreads();
        int nf1 = min(ctrl[2], F1CAP);
        float4 z4 = make_float4(0.f, 0.f, 0.f, 0.f);
        float4* a4 = (float4*)p.agg1e;
        for (int i = threadIdx.x; i < nf1 * (CH / 4); i += TPB) a4[i] = z4;
        bar_release(&ctrl[17]);
    } else bar_wait(&ctrl[17]);

    // ---- P3: e2 scan (dst in F1) + bmNd source marks ----
    for (int i = tid; i < nvec; i += nthreads) {
        int4 d4 = dst4[i];
        int ds[4] = {d4.x, d4.y, d4.z, d4.w};
#pragma unroll
        for (int k = 0; k < 4; k++) {
            int d = ds[k];
            if ((p.bmF1[d >> 5] >> (d & 31)) & 1u) {
                int s = p.src[i * 4 + k];
                atomicOr(&p.bmNd[s >> 5], 1u << (s & 31));
                int idx = atomicAdd(&ctrl[1], 1);
                if (idx < E2CAP) { p.e2s[idx] = s; p.e2d[idx] = d; }
            }
        }
    }
    for (int e = (nvec << 2) + tid; e < p.E; e += nthreads) {
        int d = p.dst[e];
        if ((p.bmF1[d >> 5] >> (d & 31)) & 1u) {
            int s = p.src[e];
            atomicOr(&p.bmNd[s >> 5], 1u << (s & 31));
            int idx = atomicAdd(&ctrl[1], 1);
            if (idx < E2CAP) { p.e2s[idx] = s; p.e2d[idx] = d; }
        }
    }
    if (bar_arrive(&ctrl[10], GRID)) bar_release(&ctrl[18]); else bar_wait(&ctrl[18]);

    // ---- P4: conditional degree scan ----
    for (int i = tid; i < nvec; i += nthreads) {
        int4 d4 = dst4[i];
        int ds[4] = {d4.x, d4.y, d4.z, d4.w};
#pragma unroll
        for (int k = 0; k < 4; k++) {
            int d = ds[k];
            if ((p.bmNd[d >> 5] >> (d & 31)) & 1u) atomicAdd(&p.deg[d], 1);
        }
    }
    for (int e = (nvec << 2) + tid; e < p.E; e += nthreads) {
        int d = p.dst[e];
        if ((p.bmNd[d >> 5] >> (d & 31)) & 1u) atomicAdd(&p.deg[d], 1);
    }
    if (bar_arrive(&ctrl[11], GRID)) bar_release(&ctrl[19]); else bar_wait(&ctrl[19]);

    // ---- P5: layer-1 edge scatter (wave shares edge, lane = channel) ----
    {
        int cnt2 = min(ctrl[1], E2CAP);
        long total = (long)cnt2 * CH;
        for (long idx = tid; idx < total; idx += nthreads) {
            int e = (int)(idx >> 6);
            int c = (int)(idx & 63);
            int w = p.e2s[e], u = p.e2d[e];
            float nrm = dinv_of(p.deg[w]) * dinv_of(p.deg[u]);
            atomicAdd(&p.agg1e[p.pos1[u] * CH + c], nrm * p.x[(size_t)w * CH + c]);
        }
    }
    // ---- bar4: last block runs h1 + tail; others arrive and exit ----
    if (!bar_arrive(&ctrl[12], GRID)) return;

    __shared__ float w1s[CH][CH];          // 16 KB
    {
        float4* wsrc = (float4*)p.W1;
        float4* wdst = (float4*)&w1s[0][0];
        for (int i = threadIdx.x; i < CH * CH / 4; i += TPB) wdst[i] = wsrc[i];
    }
    __syncthreads();

    // P6: h1[i] = relu((agg1e[i] + dinv^2 x[u]) @ W1 + b1), one wave per row
    {
        int nf1 = min(ctrl[2], F1CAP);
        int wave = threadIdx.x >> 6, lane = threadIdx.x & 63;
        for (int i = wave; i < nf1; i += TPB / 64) {
            int u = p.F1[i];
            float di = dinv_of(p.deg[u]);
            float aval = p.agg1e[i * CH + lane] + di * di * p.x[(size_t)u * CH + lane];
            float sum = p.b1[lane];
#pragma unroll 8
            for (int k = 0; k < CH; k++)
                sum += __shfl(aval, k) * w1s[k][lane];
            p.h1[i * CH + lane] = fmaxf(sum, 0.f);
        }
    }
    __syncthreads();

    // P7: layer-2 aggregate for p0/p1, h2, fc, sigmoid
    __shared__ float a[2][CH];
    __shared__ float partial[2];
    int t = threadIdx.x >> 6, j = threadIdx.x & 63;
    if (threadIdx.x < 128) {
        int pp = t ? p1 : p0;
        float dp = dinv_of(p.deg[pp]);
        float acc = dp * dp * p.h1[p.pos1[pp] * CH + j];
        int cnt1 = min(ctrl[0], E1CAP);
        for (int e = 0; e < cnt1; e++) {
            if (p.e1d[e] == pp) {
                int s = p.e1s[e];
                acc += dinv_of(p.deg[s]) * dp * p.h1[p.pos1[s] * CH + j];
            }
        }
        a[t][j] = acc;
    }
    __syncthreads();
    if (threadIdx.x < 128) {
        float sum = p.b2[j];
#pragma unroll
        for (int k = 0; k < CH; k++) sum += a[t][k] * p.W2[k * CH + j];
        float v = fmaxf(sum, 0.f);
        float pr = v * p.fcW[t * CH + j];
        for (int off = 32; off > 0; off >>= 1) pr += __shfl_down(pr, off);
        if (j == 0) partial[t] = pr;
    }
    __syncthreads();
    if (threadIdx.x == 0) {
        float z = partial[0] + partial[1] + p.fcb[0];
        p.out[0] = 1.f / (1.f + expf(-z));
    }
}

extern "C" void kernel_launch(void* const* d_in, const int* in_sizes, int n_in,
                              void* d_out, int out_size, void* d_ws, size_t ws_size,
                              hipStream_t stream) {
    Params p;
    p.x   = (const float*)d_in[0];
    const int* ei = (const int*)d_in[1];
    p.np_ = (const int*)d_in[2];
    p.W1  = (const float*)d_in[3];
    p.b1  = (const float*)d_in[4];
    p.W2  = (const float*)d_in[5];
    p.b2  = (const float*)d_in[6];
    p.fcW = (const float*)d_in[7];
    p.fcb = (const float*)d_in[8];
    p.out = (float*)d_out;

    p.N = in_sizes[0] / CH;
    p.E = in_sizes[1] / 2;
    p.src = ei;
    p.dst = ei + p.E;

    char* w = (char*)d_ws;
    size_t off = 0;
    auto alloc = [&](size_t bytes) {
        size_t o = off;
        off = (off + bytes + 255) & ~((size_t)255);
        return o;
    };
    size_t o_ctrl  = alloc(256);
    size_t o_deg   = alloc((size_t)p.N * 4);
    int bmN = (p.N + 31) / 32;
    size_t o_bmF1  = alloc((size_t)bmN * 4);
    size_t o_bmNd  = alloc((size_t)bmN * 4);
    size_t o_agg1e = alloc((size_t)F1CAP * CH * 4);
    size_t o_pos   = alloc((size_t)p.N * 4);
    size_t o_e1s   = alloc((size_t)E1CAP * 4);
    size_t o_e1d   = alloc((size_t)E1CAP * 4);
    size_t o_F1    = alloc((size_t)F1CAP * 4);
    size_t o_e2s   = alloc((size_t)E2CAP * 4);
    size_t o_e2d   = alloc((size_t)E2CAP * 4);
    size_t o_h1    = alloc((size_t)F1CAP * CH * 4);
    (void)ws_size;

    p.ctrl  = (int*)(w + o_ctrl);
    p.deg   = (int*)(w + o_deg);
    p.bmF1  = (unsigned*)(w + o_bmF1);
    p.bmNd  = (unsigned*)(w + o_bmNd);
    p.agg1e = (float*)(w + o_agg1e);
    p.pos1  = (int*)(w + o_pos);
    p.e1s   = (int*)(w + o_e1s);
    p.e1d   = (int*)(w + o_e1d);
    p.F1    = (int*)(w + o_F1);
    p.e2s   = (int*)(w + o_e2s);
    p.e2d   = (int*)(w + o_e2d);
    p.h1    = (float*)(w + o_h1);

    // zero control words + barrier counters/flags only; everything else is
    // zeroed inside the kernel (deg/bitmaps grid-wide, agg1e by bar1's last block)
    hipMemsetAsync(p.ctrl, 0, 256, stream);

    void* args[] = { &p };
    hipLaunchCooperativeKernel((void*)k_fused, dim3(GRID), dim3(TPB), args, 0, stream);
}

// Round 5
// 149.551 us; speedup vs baseline: 3.4346x; 2.2990x over previous
//
#include <hip/hip_runtime.h>
#include <math.h>

// GCN link predictor, sparse-cone evaluation (round 5).
// R3/R4 lesson: in-kernel grid-wide sync costs ~56us/barrier on MI355X
// (agent-scope fence = full L2 writeback+invalidate walk, ~27us each, since
// per-XCD L2s are non-coherent). Kernel boundaries give the same coherence
// for ~1.5us under graph replay. So: multi-kernel pipeline, 5 dispatches.
// Cross-block data consumed WITHIN a kernel (last-arrive epilogue) uses
// relaxed agent-scope atomic stores/loads (write-through to coherence point,
// no cache walk); everything crossing a kernel boundary uses plain ld/st.
//
// Dispatches:
//  M   memset 0: ctrl + bmF1 + bmNd + deg (~426 KB)
//  KA  e1 scan (dst in {p0,p1}); last-arrive block: build F1, mark bmNd,
//      zero agg1e rows
//  KB  e2 scan (dst in bmF1): collect e2, atomicOr bmNd[src]
//  KC  deg scan: deg[d]++ if bmNd[d]            (~10k atomics)
//  KD  agg1e scatter over e2; last-arrive block: h1 GEMV + layer2 + fc tail

#define CH 64
#define E1CAP 4096
#define F1CAP (E1CAP + 2)
#define E2CAP 131072
#define SCAN_GRID 512
#define KD_GRID 128
#define TPB 256

struct Params {
    const float* x; const int* src; const int* dst; int E; int N;
    const int* np_;
    const float* W1; const float* b1; const float* W2; const float* b2;
    const float* fcW; const float* fcb;
    float* out;
    int* ctrl;   // [0]=cnt_e1 [1]=cnt_e2 [2]=nf1 [8]=KA arrive [9]=KD arrive
    int* deg; unsigned* bmF1; unsigned* bmNd;
    float* agg1e; int* pos1; int* e1s; int* e1d; int* F1;
    int* e2s; int* e2d; float* h1;
};

__device__ __forceinline__ float dinv_of(int degv) { return rsqrtf((float)(degv + 1)); }

__device__ __forceinline__ void ast(int* p_, int v) {
    __hip_atomic_store(p_, v, __ATOMIC_RELAXED, __HIP_MEMORY_SCOPE_AGENT);
}
__device__ __forceinline__ int ald(const int* p_) {
    return __hip_atomic_load(p_, __ATOMIC_RELAXED, __HIP_MEMORY_SCOPE_AGENT);
}
__device__ __forceinline__ float aldf(const float* p_) {
    return __hip_atomic_load(p_, __ATOMIC_RELAXED, __HIP_MEMORY_SCOPE_AGENT);
}

// all-threads-true in the last-arriving block; no waiting, no agent fence.
// Safe because: each thread's stores are drained (vmcnt 0) before s_barrier,
// and the arrive RMW issues after barrier exit, so count==nblk-1 implies all
// blocks' (atomic, write-through) stores have reached the coherence point.
__device__ __forceinline__ bool last_arrive(int* cnt, int nblk) {
    __shared__ int is_last;
    __syncthreads();
    if (threadIdx.x == 0) {
        int t = __hip_atomic_fetch_add(cnt, 1, __ATOMIC_RELAXED, __HIP_MEMORY_SCOPE_AGENT);
        is_last = (t == nblk - 1) ? 1 : 0;
    }
    __syncthreads();
    return is_last != 0;
}

// ---- KA: e1 scan + F1 build epilogue ----
__global__ __launch_bounds__(TPB) void kA(Params p) {
    const int tid = blockIdx.x * blockDim.x + threadIdx.x;
    const int nthreads = gridDim.x * blockDim.x;
    const int p0 = p.np_[0], p1 = p.np_[1];
    const int nvec = p.E >> 2;
    const int4* dst4 = (const int4*)p.dst;

    for (int i = tid; i < nvec; i += nthreads) {
        int4 d4 = dst4[i];
        int ds[4] = {d4.x, d4.y, d4.z, d4.w};
#pragma unroll
        for (int k = 0; k < 4; k++) {
            int d = ds[k];
            if (d == p0 || d == p1) {
                int s = p.src[i * 4 + k];
                int idx = atomicAdd(&p.ctrl[0], 1);
                if (idx < E1CAP) { ast(&p.e1s[idx], s); ast(&p.e1d[idx], d); }
            }
        }
    }
    for (int e = (nvec << 2) + tid; e < p.E; e += nthreads) {
        int d = p.dst[e];
        if (d == p0 || d == p1) {
            int s = p.src[e];
            int idx = atomicAdd(&p.ctrl[0], 1);
            if (idx < E1CAP) { ast(&p.e1s[idx], s); ast(&p.e1d[idx], d); }
        }
    }

    if (!last_arrive(&p.ctrl[8], SCAN_GRID)) return;

    // epilogue (one block): build F1 = {p0,p1} U src(e1)
    int cnt1 = min(ald(&p.ctrl[0]), E1CAP);
    for (int g = threadIdx.x; g < cnt1 + 2; g += TPB) {
        int u = (g < cnt1) ? ald(&p.e1s[g]) : ((g - cnt1) ? p1 : p0);
        unsigned bit = 1u << (u & 31);
        unsigned old = atomicOr(&p.bmF1[u >> 5], bit);
        if (!(old & bit)) {
            atomicOr(&p.bmNd[u >> 5], bit);
            int i = atomicAdd(&p.ctrl[2], 1);
            p.F1[i] = u;       // plain: read by later kernels only
            p.pos1[u] = i;
        }
    }
    __syncthreads();
    int nf1 = min(ald(&p.ctrl[2]), F1CAP);
    float4 z4 = make_float4(0.f, 0.f, 0.f, 0.f);
    float4* a4 = (float4*)p.agg1e;
    for (int i = threadIdx.x; i < nf1 * (CH / 4); i += TPB) a4[i] = z4;
}

// ---- KB: e2 scan ----
__global__ __launch_bounds__(TPB) void kB(Params p) {
    const int tid = blockIdx.x * blockDim.x + threadIdx.x;
    const int nthreads = gridDim.x * blockDim.x;
    const int nvec = p.E >> 2;
    const int4* dst4 = (const int4*)p.dst;
    for (int i = tid; i < nvec; i += nthreads) {
        int4 d4 = dst4[i];
        int ds[4] = {d4.x, d4.y, d4.z, d4.w};
#pragma unroll
        for (int k = 0; k < 4; k++) {
            int d = ds[k];
            if ((p.bmF1[d >> 5] >> (d & 31)) & 1u) {
                int s = p.src[i * 4 + k];
                atomicOr(&p.bmNd[s >> 5], 1u << (s & 31));
                int idx = atomicAdd(&p.ctrl[1], 1);
                if (idx < E2CAP) { p.e2s[idx] = s; p.e2d[idx] = d; }
            }
        }
    }
    for (int e = (nvec << 2) + tid; e < p.E; e += nthreads) {
        int d = p.dst[e];
        if ((p.bmF1[d >> 5] >> (d & 31)) & 1u) {
            int s = p.src[e];
            atomicOr(&p.bmNd[s >> 5], 1u << (s & 31));
            int idx = atomicAdd(&p.ctrl[1], 1);
            if (idx < E2CAP) { p.e2s[idx] = s; p.e2d[idx] = d; }
        }
    }
}

// ---- KC: conditional degree scan ----
__global__ __launch_bounds__(TPB) void kC(Params p) {
    const int tid = blockIdx.x * blockDim.x + threadIdx.x;
    const int nthreads = gridDim.x * blockDim.x;
    const int nvec = p.E >> 2;
    const int4* dst4 = (const int4*)p.dst;
    for (int i = tid; i < nvec; i += nthreads) {
        int4 d4 = dst4[i];
        int ds[4] = {d4.x, d4.y, d4.z, d4.w};
#pragma unroll
        for (int k = 0; k < 4; k++) {
            int d = ds[k];
            if ((p.bmNd[d >> 5] >> (d & 31)) & 1u) atomicAdd(&p.deg[d], 1);
        }
    }
    for (int e = (nvec << 2) + tid; e < p.E; e += nthreads) {
        int d = p.dst[e];
        if ((p.bmNd[d >> 5] >> (d & 31)) & 1u) atomicAdd(&p.deg[d], 1);
    }
}

// ---- KD: agg1e scatter + (last block) h1 GEMV + tail ----
__global__ __launch_bounds__(TPB) void kD(Params p) {
    const int tid = blockIdx.x * blockDim.x + threadIdx.x;
    const int nthreads = gridDim.x * blockDim.x;

    {
        int cnt2 = min(p.ctrl[1], E2CAP);   // plain read: written in prev kernel
        long total = (long)cnt2 * CH;
        for (long idx = tid; idx < total; idx += nthreads) {
            int e = (int)(idx >> 6);        // wave shares edge; lane = channel
            int c = (int)(idx & 63);
            int w = p.e2s[e], u = p.e2d[e];
            float nrm = dinv_of(p.deg[w]) * dinv_of(p.deg[u]);
            atomicAdd(&p.agg1e[p.pos1[u] * CH + c], nrm * p.x[(size_t)w * CH + c]);
        }
    }

    if (!last_arrive(&p.ctrl[9], KD_GRID)) return;

    // ---- epilogue block: h1 for all F1 rows, then layer-2 + fc + sigmoid ----
    const int p0 = p.np_[0], p1 = p.np_[1];
    int nf1 = min(p.ctrl[2], F1CAP);
    int wave = threadIdx.x >> 6, lane = threadIdx.x & 63;
    for (int i = wave; i < nf1; i += TPB / 64) {
        int u = p.F1[i];
        float di = dinv_of(p.deg[u]);
        // agg1e was atomically accumulated within THIS kernel -> atomic load
        float aval = aldf(&p.agg1e[i * CH + lane]) + di * di * p.x[(size_t)u * CH + lane];
        float sum = p.b1[lane];
#pragma unroll 8
        for (int k = 0; k < CH; k++)
            sum += __shfl(aval, k) * p.W1[k * CH + lane];
        p.h1[i * CH + lane] = fmaxf(sum, 0.f);   // same-block producer/consumer
    }
    __syncthreads();

    __shared__ float a[2][CH];
    __shared__ float partial[2];
    int t = threadIdx.x >> 6, j = threadIdx.x & 63;
    if (threadIdx.x < 128) {
        int pp = t ? p1 : p0;
        float dp = dinv_of(p.deg[pp]);
        float acc = dp * dp * p.h1[p.pos1[pp] * CH + j];
        int cnt1 = min(p.ctrl[0], E1CAP);
        for (int e = 0; e < cnt1; e++) {
            if (p.e1d[e] == pp) {            // written in KA (prev kernel) -> plain ok
                int s = p.e1s[e];
                acc += dinv_of(p.deg[s]) * dp * p.h1[p.pos1[s] * CH + j];
            }
        }
        a[t][j] = acc;
    }
    __syncthreads();
    if (threadIdx.x < 128) {
        float sum = p.b2[j];
#pragma unroll
        for (int k = 0; k < CH; k++) sum += a[t][k] * p.W2[k * CH + j];
        float v = fmaxf(sum, 0.f);
        float pr = v * p.fcW[t * CH + j];
        for (int off = 32; off > 0; off >>= 1) pr += __shfl_down(pr, off);
        if (j == 0) partial[t] = pr;
    }
    __syncthreads();
    if (threadIdx.x == 0) {
        float z = partial[0] + partial[1] + p.fcb[0];
        p.out[0] = 1.f / (1.f + expf(-z));
    }
}

extern "C" void kernel_launch(void* const* d_in, const int* in_sizes, int n_in,
                              void* d_out, int out_size, void* d_ws, size_t ws_size,
                              hipStream_t stream) {
    Params p;
    p.x   = (const float*)d_in[0];
    const int* ei = (const int*)d_in[1];
    p.np_ = (const int*)d_in[2];
    p.W1  = (const float*)d_in[3];
    p.b1  = (const float*)d_in[4];
    p.W2  = (const float*)d_in[5];
    p.b2  = (const float*)d_in[6];
    p.fcW = (const float*)d_in[7];
    p.fcb = (const float*)d_in[8];
    p.out = (float*)d_out;

    p.N = in_sizes[0] / CH;
    p.E = in_sizes[1] / 2;
    p.src = ei;
    p.dst = ei + p.E;

    char* w = (char*)d_ws;
    size_t off = 0;
    auto alloc = [&](size_t bytes) {
        size_t o = off;
        off = (off + bytes + 255) & ~((size_t)255);
        return o;
    };
    // --- zeroed region (one memset): ctrl, bitmaps, deg ---
    size_t o_ctrl  = alloc(256);
    int bmN = (p.N + 31) / 32;
    size_t o_bmF1  = alloc((size_t)bmN * 4);
    size_t o_bmNd  = alloc((size_t)bmN * 4);
    size_t o_deg   = alloc((size_t)p.N * 4);
    size_t zero_end = off;
    // --- rest ---
    size_t o_agg1e = alloc((size_t)F1CAP * CH * 4);
    size_t o_pos   = alloc((size_t)p.N * 4);
    size_t o_e1s   = alloc((size_t)E1CAP * 4);
    size_t o_e1d   = alloc((size_t)E1CAP * 4);
    size_t o_F1    = alloc((size_t)F1CAP * 4);
    size_t o_e2s   = alloc((size_t)E2CAP * 4);
    size_t o_e2d   = alloc((size_t)E2CAP * 4);
    size_t o_h1    = alloc((size_t)F1CAP * CH * 4);
    (void)ws_size;

    p.ctrl  = (int*)(w + o_ctrl);
    p.bmF1  = (unsigned*)(w + o_bmF1);
    p.bmNd  = (unsigned*)(w + o_bmNd);
    p.deg   = (int*)(w + o_deg);
    p.agg1e = (float*)(w + o_agg1e);
    p.pos1  = (int*)(w + o_pos);
    p.e1s   = (int*)(w + o_e1s);
    p.e1d   = (int*)(w + o_e1d);
    p.F1    = (int*)(w + o_F1);
    p.e2s   = (int*)(w + o_e2s);
    p.e2d   = (int*)(w + o_e2d);
    p.h1    = (float*)(w + o_h1);

    hipMemsetAsync(d_ws, 0, zero_end, stream);
    kA<<<SCAN_GRID, TPB, 0, stream>>>(p);
    kB<<<SCAN_GRID, TPB, 0, stream>>>(p);
    kC<<<SCAN_GRID, TPB, 0, stream>>>(p);
    kD<<<KD_GRID, TPB, 0, stream>>>(p);
}

// Round 6
// 134.190 us; speedup vs baseline: 3.8278x; 1.1145x over previous
//
#include <hip/hip_runtime.h>
#include <math.h>

// GCN link predictor, sparse-cone evaluation (round 6).
// R5 lesson: last-arrive epilogues + shrunken scan grids regressed vs the
// plain R2 pipeline. This round: pure kernel-boundary coherence (no
// cross-block sync of any kind), R2's proven 1563-block scans, and the tail
// (h1 GEMV + layer-2 + fc + sigmoid) compressed into ONE 1-block kernel.
//
// Dispatches (7):
//  M   memset 0: ctrl + bmF1 + bmNd + deg (~426 KB)
//  K1  e1 scan: dst in {p0,p1} -> e1 list
//  K2  (1 block) build F1 = {p0,p1} U src(e1); pos1; bmF1/bmNd; zero agg1e
//  K3  e2 scan: dst in bmF1 -> e2 list; atomicOr bmNd[src]
//  K4  deg scan: deg[d]++ if bmNd[d]          (~10k atomics)
//  K5  agg1e scatter over e2 (wave=edge, lane=channel, global atomics)
//  K6  (1 block) h1 = relu(agg1@W1+b1) for F1 rows; layer-2 agg for p0/p1;
//      h2 = relu(@W2+b2); out = sigmoid(concat . fcW + fcb)

#define CH 64
#define E1CAP 4096
#define F1CAP (E1CAP + 2)
#define E2CAP 131072
#define TPB 256

struct Params {
    const float* x; const int* src; const int* dst; int E; int N;
    const int* np_;
    const float* W1; const float* b1; const float* W2; const float* b2;
    const float* fcW; const float* fcb;
    float* out;
    int* ctrl;   // [0]=cnt_e1 [1]=cnt_e2 [2]=nf1
    int* deg; unsigned* bmF1; unsigned* bmNd;
    float* agg1e; int* pos1; int* e1s; int* e1d; int* F1;
    int* e2s; int* e2d; float* h1;
};

__device__ __forceinline__ float dinv_of(int degv) { return rsqrtf((float)(degv + 1)); }

// ---- K1: e1 scan ----
__global__ __launch_bounds__(TPB) void k1_e1(Params p) {
    const int tid = blockIdx.x * blockDim.x + threadIdx.x;
    const int nthreads = gridDim.x * blockDim.x;
    const int p0 = p.np_[0], p1 = p.np_[1];
    const int nvec = p.E >> 2;
    const int4* dst4 = (const int4*)p.dst;
    for (int i = tid; i < nvec; i += nthreads) {
        int4 d4 = dst4[i];
        int ds[4] = {d4.x, d4.y, d4.z, d4.w};
#pragma unroll
        for (int k = 0; k < 4; k++) {
            int d = ds[k];
            if (d == p0 || d == p1) {
                int s = p.src[i * 4 + k];
                int idx = atomicAdd(&p.ctrl[0], 1);
                if (idx < E1CAP) { p.e1s[idx] = s; p.e1d[idx] = d; }
            }
        }
    }
    for (int e = (nvec << 2) + tid; e < p.E; e += nthreads) {
        int d = p.dst[e];
        if (d == p0 || d == p1) {
            int s = p.src[e];
            int idx = atomicAdd(&p.ctrl[0], 1);
            if (idx < E1CAP) { p.e1s[idx] = s; p.e1d[idx] = d; }
        }
    }
}

// ---- K2: build F1 (single block) + zero agg1e rows ----
__global__ __launch_bounds__(TPB) void k2_build(Params p) {
    int cnt1 = min(p.ctrl[0], E1CAP);
    const int p0 = p.np_[0], p1 = p.np_[1];
    for (int g = threadIdx.x; g < cnt1 + 2; g += TPB) {
        int u = (g < cnt1) ? p.e1s[g] : ((g - cnt1) ? p1 : p0);
        unsigned bit = 1u << (u & 31);
        unsigned old = atomicOr(&p.bmF1[u >> 5], bit);
        if (!(old & bit)) {
            atomicOr(&p.bmNd[u >> 5], bit);
            int i = atomicAdd(&p.ctrl[2], 1);
            p.F1[i] = u;
            p.pos1[u] = i;
        }
    }
    __syncthreads();
    int nf1 = min(p.ctrl[2], F1CAP);
    float4 z4 = make_float4(0.f, 0.f, 0.f, 0.f);
    float4* a4 = (float4*)p.agg1e;
    for (int i = threadIdx.x; i < nf1 * (CH / 4); i += TPB) a4[i] = z4;
}

// ---- K3: e2 scan + bmNd source marks ----
__global__ __launch_bounds__(TPB) void k3_e2(Params p) {
    const int tid = blockIdx.x * blockDim.x + threadIdx.x;
    const int nthreads = gridDim.x * blockDim.x;
    const int nvec = p.E >> 2;
    const int4* dst4 = (const int4*)p.dst;
    for (int i = tid; i < nvec; i += nthreads) {
        int4 d4 = dst4[i];
        int ds[4] = {d4.x, d4.y, d4.z, d4.w};
#pragma unroll
        for (int k = 0; k < 4; k++) {
            int d = ds[k];
            if ((p.bmF1[d >> 5] >> (d & 31)) & 1u) {
                int s = p.src[i * 4 + k];
                atomicOr(&p.bmNd[s >> 5], 1u << (s & 31));
                int idx = atomicAdd(&p.ctrl[1], 1);
                if (idx < E2CAP) { p.e2s[idx] = s; p.e2d[idx] = d; }
            }
        }
    }
    for (int e = (nvec << 2) + tid; e < p.E; e += nthreads) {
        int d = p.dst[e];
        if ((p.bmF1[d >> 5] >> (d & 31)) & 1u) {
            int s = p.src[e];
            atomicOr(&p.bmNd[s >> 5], 1u << (s & 31));
            int idx = atomicAdd(&p.ctrl[1], 1);
            if (idx < E2CAP) { p.e2s[idx] = s; p.e2d[idx] = d; }
        }
    }
}

// ---- K4: conditional degree scan ----
__global__ __launch_bounds__(TPB) void k4_deg(Params p) {
    const int tid = blockIdx.x * blockDim.x + threadIdx.x;
    const int nthreads = gridDim.x * blockDim.x;
    const int nvec = p.E >> 2;
    const int4* dst4 = (const int4*)p.dst;
    for (int i = tid; i < nvec; i += nthreads) {
        int4 d4 = dst4[i];
        int ds[4] = {d4.x, d4.y, d4.z, d4.w};
#pragma unroll
        for (int k = 0; k < 4; k++) {
            int d = ds[k];
            if ((p.bmNd[d >> 5] >> (d & 31)) & 1u) atomicAdd(&p.deg[d], 1);
        }
    }
    for (int e = (nvec << 2) + tid; e < p.E; e += nthreads) {
        int d = p.dst[e];
        if ((p.bmNd[d >> 5] >> (d & 31)) & 1u) atomicAdd(&p.deg[d], 1);
    }
}

// ---- K5: agg1e scatter (wave shares edge, lane = channel) ----
__global__ __launch_bounds__(TPB) void k5_scatter(Params p) {
    const int tid = blockIdx.x * blockDim.x + threadIdx.x;
    const int nthreads = gridDim.x * blockDim.x;
    int cnt2 = min(p.ctrl[1], E2CAP);
    long total = (long)cnt2 * CH;
    for (long idx = tid; idx < total; idx += nthreads) {
        int e = (int)(idx >> 6);
        int c = (int)(idx & 63);
        int w = p.e2s[e], u = p.e2d[e];
        float nrm = dinv_of(p.deg[w]) * dinv_of(p.deg[u]);
        atomicAdd(&p.agg1e[p.pos1[u] * CH + c], nrm * p.x[(size_t)w * CH + c]);
    }
}

// ---- K6: tail (single block): h1 GEMV + layer-2 + fc + sigmoid ----
__global__ __launch_bounds__(TPB) void k6_tail(Params p) {
    const int p0 = p.np_[0], p1 = p.np_[1];
    int nf1 = min(p.ctrl[2], F1CAP);
    int wave = threadIdx.x >> 6, lane = threadIdx.x & 63;

    // h1[i] = relu((agg1e[i] + dinv^2 x[u]) @ W1 + b1), one wave per row
    for (int i = wave; i < nf1; i += TPB / 64) {
        int u = p.F1[i];
        float di = dinv_of(p.deg[u]);
        float aval = p.agg1e[i * CH + lane] + di * di * p.x[(size_t)u * CH + lane];
        float sum = p.b1[lane];
#pragma unroll 8
        for (int k = 0; k < CH; k++)
            sum += __shfl(aval, k) * p.W1[k * CH + lane];
        p.h1[i * CH + lane] = fmaxf(sum, 0.f);
    }
    __syncthreads();

    __shared__ float a[2][CH];
    __shared__ float partial[2];
    int t = threadIdx.x >> 6, j = threadIdx.x & 63;
    if (threadIdx.x < 128) {
        int pp = t ? p1 : p0;
        float dp = dinv_of(p.deg[pp]);
        float acc = dp * dp * p.h1[p.pos1[pp] * CH + j];
        int cnt1 = min(p.ctrl[0], E1CAP);
        for (int e = 0; e < cnt1; e++) {
            if (p.e1d[e] == pp) {
                int s = p.e1s[e];
                acc += dinv_of(p.deg[s]) * dp * p.h1[p.pos1[s] * CH + j];
            }
        }
        a[t][j] = acc;
    }
    __syncthreads();
    if (threadIdx.x < 128) {
        float sum = p.b2[j];
#pragma unroll
        for (int k = 0; k < CH; k++) sum += a[t][k] * p.W2[k * CH + j];
        float v = fmaxf(sum, 0.f);
        float pr = v * p.fcW[t * CH + j];
        for (int off = 32; off > 0; off >>= 1) pr += __shfl_down(pr, off);
        if (j == 0) partial[t] = pr;
    }
    __syncthreads();
    if (threadIdx.x == 0) {
        float z = partial[0] + partial[1] + p.fcb[0];
        p.out[0] = 1.f / (1.f + expf(-z));
    }
}

extern "C" void kernel_launch(void* const* d_in, const int* in_sizes, int n_in,
                              void* d_out, int out_size, void* d_ws, size_t ws_size,
                              hipStream_t stream) {
    Params p;
    p.x   = (const float*)d_in[0];
    const int* ei = (const int*)d_in[1];
    p.np_ = (const int*)d_in[2];
    p.W1  = (const float*)d_in[3];
    p.b1  = (const float*)d_in[4];
    p.W2  = (const float*)d_in[5];
    p.b2  = (const float*)d_in[6];
    p.fcW = (const float*)d_in[7];
    p.fcb = (const float*)d_in[8];
    p.out = (float*)d_out;

    p.N = in_sizes[0] / CH;
    p.E = in_sizes[1] / 2;
    p.src = ei;
    p.dst = ei + p.E;

    char* w = (char*)d_ws;
    size_t off = 0;
    auto alloc = [&](size_t bytes) {
        size_t o = off;
        off = (off + bytes + 255) & ~((size_t)255);
        return o;
    };
    // --- zeroed region (one memset): ctrl, bitmaps, deg (~426 KB) ---
    size_t o_ctrl  = alloc(256);
    int bmN = (p.N + 31) / 32;
    size_t o_bmF1  = alloc((size_t)bmN * 4);
    size_t o_bmNd  = alloc((size_t)bmN * 4);
    size_t o_deg   = alloc((size_t)p.N * 4);
    size_t zero_end = off;
    // --- rest (uninitialized / lazily initialized) ---
    size_t o_agg1e = alloc((size_t)F1CAP * CH * 4);
    size_t o_pos   = alloc((size_t)p.N * 4);
    size_t o_e1s   = alloc((size_t)E1CAP * 4);
    size_t o_e1d   = alloc((size_t)E1CAP * 4);
    size_t o_F1    = alloc((size_t)F1CAP * 4);
    size_t o_e2s   = alloc((size_t)E2CAP * 4);
    size_t o_e2d   = alloc((size_t)E2CAP * 4);
    size_t o_h1    = alloc((size_t)F1CAP * CH * 4);
    (void)ws_size;

    p.ctrl  = (int*)(w + o_ctrl);
    p.bmF1  = (unsigned*)(w + o_bmF1);
    p.bmNd  = (unsigned*)(w + o_bmNd);
    p.deg   = (int*)(w + o_deg);
    p.agg1e = (float*)(w + o_agg1e);
    p.pos1  = (int*)(w + o_pos);
    p.e1s   = (int*)(w + o_e1s);
    p.e1d   = (int*)(w + o_e1d);
    p.F1    = (int*)(w + o_F1);
    p.e2s   = (int*)(w + o_e2s);
    p.e2d   = (int*)(w + o_e2d);
    p.h1    = (float*)(w + o_h1);

    hipMemsetAsync(d_ws, 0, zero_end, stream);

    int scanBlocks = (p.E / 4 + TPB - 1) / TPB;   // 1563 at E=1.6M (R2-proven)
    if (scanBlocks < 1) scanBlocks = 1;
    if (scanBlocks > 8192) scanBlocks = 8192;

    k1_e1     <<<scanBlocks, TPB, 0, stream>>>(p);
    k2_build  <<<1,          TPB, 0, stream>>>(p);
    k3_e2     <<<scanBlocks, TPB, 0, stream>>>(p);
    k4_deg    <<<scanBlocks, TPB, 0, stream>>>(p);
    k5_scatter<<<256,        TPB, 0, stream>>>(p);
    k6_tail   <<<1,          TPB, 0, stream>>>(p);
}